// Round 12
// baseline (262.920 us; speedup 1.0000x reference)
//
#include <hip/hip_runtime.h>
#include <hip/hip_bf16.h>
#include <math.h>

typedef __attribute__((ext_vector_type(4))) float f32x4;
typedef __attribute__((ext_vector_type(8))) short s16x8;
typedef __attribute__((ext_vector_type(8))) unsigned short u16x8;

#define CAP 48   // bucket capacity per dst node; deg = 1 + Binomial(600k, 1/50k), P(>=48) ~ 1e-15

__device__ inline unsigned short f2b(float f) {
    union { float f; unsigned u; } x; x.f = f;
    unsigned r = x.u + 0x7FFF + ((x.u >> 16) & 1);   // RNE
    return (unsigned short)(r >> 16);
}
__device__ inline float b2f(unsigned short b) {
    union { unsigned u; float f; } x; x.u = ((unsigned)b) << 16; return x.f;
}

__device__ inline void gload_lds16(const void* g, void* l) {
    __builtin_amdgcn_global_load_lds(
        (const __attribute__((address_space(1))) void*)g,
        (__attribute__((address_space(3))) void*)l, 16, 0, 0);
}

// ---------------- wide bf16 MFMA GEMM: 128x512 tile, 16 waves (1024 thr) ----------------
// For GEMM1/GEMM2 (Nn=512): single col-block -> A read exactly ONCE.
// A: aflt=0 -> bf16 [M,K]; aflt=1 -> f32 [M,K] converted during reg-staged LDS write.
// bf16 split write: col<split -> C (stride split), else C2 (stride Nn-split).
#define WBM 128
#define WBN 512
#define WBK 64

__global__ __launch_bounds__(1024) void gemm_mfma_w(
    const void* __restrict__ Aptr, const unsigned short* __restrict__ Bt,
    void* __restrict__ Cout, void* __restrict__ Cout2,
    int M, int K, int split, int aflt)
{
    __shared__ unsigned short As[WBM * WBK];   // 16 KB
    __shared__ unsigned short Bs[WBN * WBK];   // 64 KB
    const int tid = threadIdx.x;
    const int lane = tid & 63;
    const int w = tid >> 6, wm = w >> 3, wn = w & 7;   // 2 x 8 waves of 64x64
    const int row0 = blockIdx.y * WBM;
    const int l15 = lane & 15, l7 = lane & 7, lhi = lane >> 4;

    f32x4 acc[4][4] = {};

    for (int k0 = 0; k0 < K; k0 += WBK) {
        if (aflt == 0) {
            const unsigned short* A = (const unsigned short*)Aptr;
            int L = tid;                             // 1024 chunks, 1 pass
            int row = L >> 3;
            int c = (L & 7) ^ (row & 7);
            int gr = row0 + row; gr = gr < M ? gr : M - 1;
            gload_lds16(A + (size_t)gr * K + k0 + c * 8, (char*)As + L * 16);
        } else {
            const float* A = (const float*)Aptr;
            int L = tid;
            int row = L >> 3;
            int c = (L & 7) ^ (row & 7);
            int gr = row0 + row; gr = gr < M ? gr : M - 1;
            const float* ap = A + (size_t)gr * K + k0 + c * 8;
            float4 va = *(const float4*)ap;
            float4 vb = *(const float4*)(ap + 4);
            ushort4 o0 = { f2b(va.x), f2b(va.y), f2b(va.z), f2b(va.w) };
            ushort4 o1 = { f2b(vb.x), f2b(vb.y), f2b(vb.z), f2b(vb.w) };
            *(ushort4*)((char*)As + L * 16)     = o0;
            *(ushort4*)((char*)As + L * 16 + 8) = o1;
        }
        #pragma unroll
        for (int i = 0; i < 4; i++) {               // B: 4096 chunks
            int L = i * 1024 + tid;
            int row = L >> 3;                       // 0..511
            int c = (L & 7) ^ (row & 7);
            gload_lds16(Bt + (size_t)row * K + k0 + c * 8, (char*)Bs + L * 16);
        }
        __syncthreads();                            // drains vmcnt + lgkmcnt
        #pragma unroll
        for (int kk = 0; kk < 2; kk++) {
            s16x8 af[4], bf[4];
            #pragma unroll
            for (int i = 0; i < 4; i++) {
                int slot = (wm * 64 + i * 16 + l15) * 8 + ((kk * 4 + lhi) ^ l7);
                af[i] = *(const s16x8*)((const char*)As + slot * 16);
            }
            #pragma unroll
            for (int j = 0; j < 4; j++) {
                int slot = (wn * 64 + j * 16 + l15) * 8 + ((kk * 4 + lhi) ^ l7);
                bf[j] = *(const s16x8*)((const char*)Bs + slot * 16);
            }
            #pragma unroll
            for (int i = 0; i < 4; i++)
                #pragma unroll
                for (int j = 0; j < 4; j++)
                    acc[i][j] = __builtin_amdgcn_mfma_f32_16x16x32_bf16(
                        af[i], bf[j], acc[i][j], 0, 0, 0);
        }
        __syncthreads();
    }

    unsigned short* C  = (unsigned short*)Cout;
    unsigned short* C2 = (unsigned short*)Cout2;
    const int ld2 = WBN - split;
    #pragma unroll
    for (int i = 0; i < 4; i++)
        #pragma unroll
        for (int r = 0; r < 4; r++) {
            int row = row0 + wm * 64 + i * 16 + lhi * 4 + r;
            if (row >= M) continue;
            #pragma unroll
            for (int j = 0; j < 4; j++) {
                int col = wn * 64 + j * 16 + l15;
                unsigned short val = f2b(acc[i][j][r]);
                if (col < split) C[(size_t)row * split + col] = val;
                else             C2[(size_t)row * ld2 + (col - split)] = val;
            }
        }
}

// ---------------- narrow GEMM (GEMM3 only): 128x256 tile, 8 waves ----------------
// f32 + bias + sigmoid -> C, only col<split stored, stride split
#define GBM 128
#define GBN 256
#define GBK 64

__global__ __launch_bounds__(512) void gemm_mfma(
    const unsigned short* __restrict__ A, const unsigned short* __restrict__ Bt,
    const float* __restrict__ bias, float* __restrict__ C,
    int M, int K, int split)
{
    __shared__ unsigned short As[GBM * GBK];   // 16 KB
    __shared__ unsigned short Bs[GBN * GBK];   // 32 KB
    const int tid = threadIdx.x;
    const int lane = tid & 63;
    const int w = tid >> 6, wm = w >> 2, wn = w & 3;   // 2 x 4 waves of 64x64
    const int row0 = blockIdx.y * GBM;
    const int l15 = lane & 15, l7 = lane & 7, lhi = lane >> 4;

    f32x4 acc[4][4] = {};

    for (int k0 = 0; k0 < K; k0 += GBK) {
        #pragma unroll
        for (int i = 0; i < 2; i++) {               // A: 1024 chunks of 16B
            int L = i * 512 + tid;
            int row = L >> 3;
            int c = (L & 7) ^ (row & 7);
            int gr = row0 + row; gr = gr < M ? gr : M - 1;
            gload_lds16(A + (size_t)gr * K + k0 + c * 8, (char*)As + L * 16);
        }
        #pragma unroll
        for (int i = 0; i < 4; i++) {               // B: 2048 chunks
            int L = i * 512 + tid;
            int row = L >> 3;                       // 0..255
            int c = (L & 7) ^ (row & 7);
            gload_lds16(Bt + (size_t)row * K + k0 + c * 8, (char*)Bs + L * 16);
        }
        __syncthreads();
        #pragma unroll
        for (int kk = 0; kk < 2; kk++) {
            s16x8 af[4], bf[4];
            #pragma unroll
            for (int i = 0; i < 4; i++) {
                int slot = (wm * 64 + i * 16 + l15) * 8 + ((kk * 4 + lhi) ^ l7);
                af[i] = *(const s16x8*)((const char*)As + slot * 16);
            }
            #pragma unroll
            for (int j = 0; j < 4; j++) {
                int slot = (wn * 64 + j * 16 + l15) * 8 + ((kk * 4 + lhi) ^ l7);
                bf[j] = *(const s16x8*)((const char*)Bs + slot * 16);
            }
            #pragma unroll
            for (int i = 0; i < 4; i++)
                #pragma unroll
                for (int j = 0; j < 4; j++)
                    acc[i][j] = __builtin_amdgcn_mfma_f32_16x16x32_bf16(
                        af[i], bf[j], acc[i][j], 0, 0, 0);
        }
        __syncthreads();
    }

    #pragma unroll
    for (int i = 0; i < 4; i++)
        #pragma unroll
        for (int r = 0; r < 4; r++) {
            int row = row0 + wm * 64 + i * 16 + lhi * 4 + r;
            if (row >= M) continue;
            #pragma unroll
            for (int j = 0; j < 4; j++) {
                int col = wn * 64 + j * 16 + l15;
                if (col >= split) continue;
                float v = acc[i][j][r] + bias[col];
                C[(size_t)row * split + col] = 1.f / (1.f + __expf(-v));
            }
        }
}

// ---------------- prep + bucket-fill, one segmented launch ----------------
// [0,32):     Wcat1 = [Wl1^T; Wr1^T] bf16, 2048 elems/block
// [32,96):    Wcat2 = [Wl2^T; Wr2^T] bf16, 2048 elems/block
// [96,352):   W34t[n,:] = bf16((W3@W4)[:,n]) for n<40 else 0 (256 rows); b34
// [352,2892): bucket fill (cnt must be pre-zeroed via memset)
#define PB 32
#define PC 96
#define PD 352
#define PEND 2892

__global__ __launch_bounds__(256) void k_prep(
    const float* __restrict__ Wl1, const float* __restrict__ Wr1,
    const float* __restrict__ Wl2, const float* __restrict__ Wr2,
    const float* __restrict__ W3,  const float* __restrict__ W4,
    const float* __restrict__ b3,  const float* __restrict__ b4,
    const int* __restrict__ src,   const int* __restrict__ dstv, int E,
    unsigned short* __restrict__ Wcat1, unsigned short* __restrict__ Wcat2,
    unsigned short* __restrict__ W34t, float* __restrict__ b34,
    int* __restrict__ cnt, int* __restrict__ colA)
{
    __shared__ float w4c[128];
    const int b = blockIdx.x, tid = threadIdx.x;

    if (b < PB) {                                  // Wcat1 (65536)
        int base = b * 2048 + tid * 8;
        #pragma unroll
        for (int j = 0; j < 8; j++) {
            int e = base + j;
            int ep = e & 32767, n = ep >> 7, k = ep & 127;
            const float* srcp = (e < 32768) ? Wl1 : Wr1;
            Wcat1[e] = f2b(srcp[k * 256 + n]);
        }
    } else if (b < PC) {                           // Wcat2 (131072)
        int base = (b - PB) * 2048 + tid * 8;
        #pragma unroll
        for (int j = 0; j < 8; j++) {
            int e = base + j;
            int ep = e & 65535, n = ep >> 8, k = ep & 255;
            const float* srcp = (e < 65536) ? Wl2 : Wr2;
            Wcat2[e] = f2b(srcp[k * 256 + n]);
        }
    } else if (b < PD) {                           // W34 fold, n = b - PC (0..255)
        int n = b - PC;
        if (n < 40) {
            if (tid < 128) w4c[tid] = W4[tid * 40 + n];
            __syncthreads();
            float s = 0.f;
            const float4* p = (const float4*)&W3[(size_t)tid * 128];
            #pragma unroll
            for (int j = 0; j < 32; j++) {
                float4 v = p[j];
                s = fmaf(v.x, w4c[j * 4 + 0], s);
                s = fmaf(v.y, w4c[j * 4 + 1], s);
                s = fmaf(v.z, w4c[j * 4 + 2], s);
                s = fmaf(v.w, w4c[j * 4 + 3], s);
            }
            W34t[(size_t)n * 256 + tid] = f2b(s);
            if (tid == 0) {
                float t = b4[n];
                for (int j = 0; j < 128; j++) t = fmaf(b3[j], w4c[j], t);
                b34[n] = t;
            }
        } else {
            W34t[(size_t)n * 256 + tid] = 0;       // zero pad rows 40..255
        }
    } else {                                       // bucket fill
        int e = (b - PD) * 256 + tid;
        if (e < E) {
            int d = dstv[e];
            int slot = atomicAdd(&cnt[d], 1);
            __builtin_nontemporal_store(src[e] << 8, &colA[d * CAP + slot]);
        }
    }
}

// ---------------- fused attention (R11-exact: 2-deep, 40 VGPR floor config) ----------------
// One wave per dst node; two edge streams (one per 32-lane half), lane holds
// 8 channels (16B gathers), unroll x2 -> 4 gathers in flight per wave. Scores
// in exp2 domain (log2e folded into att). Defer-max (THR=8): fast path does
// single-FMA accumulate + one exp2; rescale only when ballot sees dot>m+8.
// Bracketed floor: VALU diet null (R6), extra VALU +7us (R7), 4-deep +3.4us (R10).
__global__ __launch_bounds__(256) void k_attn(const unsigned short* __restrict__ xl,
    const unsigned short* __restrict__ xr, const float* __restrict__ att,
    const int* __restrict__ cnt, const int* __restrict__ colA,
    const float* __restrict__ bias, int Nn, unsigned short* __restrict__ outp)
{
    int n = blockIdx.x * 4 + (threadIdx.x >> 6);
    int lane = threadIdx.x & 63;
    if (n >= Nn) return;
    const int lh = lane & 31;        // lane-in-half: channels lh*8 .. lh*8+7
    const int h  = lane >> 5;        // edge-stream id
    int r0 = n * CAP;
    int r1 = r0 + cnt[n];            // cnt >= 1 always (self-loop)

    const float LOG2E = 1.4426950408889634f;
    u16x8 xb = *(const u16x8*)&xr[(size_t)n * 256 + lh * 8];
    float xrv[8], w[8];
    #pragma unroll
    for (int k = 0; k < 8; k++) { xrv[k] = b2f(xb[k]); w[k] = att[lh * 8 + k] * LOG2E; }

    float m = -INFINITY, l = 0.f;
    float acc[8] = {};

    auto update = [&](const u16x8& vb) {
        float v[8];
        #pragma unroll
        for (int k = 0; k < 8; k++) v[k] = b2f(vb[k]);
        float dot = 0.f;
        #pragma unroll
        for (int k = 0; k < 8; k++) {
            float t = v[k] + xrv[k];
            t = fmaxf(t, 0.2f * t);          // leaky_relu, slope<1
            dot = fmaf(t, w[k], dot);
        }
        #pragma unroll
        for (int off = 1; off <= 8; off <<= 1) dot += __shfl_xor(dot, off);
        // dot uniform within each 16-lane head group, exp2 domain
        if (__ballot(dot > m + 8.f)) {       // rare rescale path
            float mn = fmaxf(m, dot);
            float sc = exp2f(m - mn);        // 0 on first edge (m=-inf)
            float we = exp2f(dot - mn);
            l = l * sc + we;
            #pragma unroll
            for (int k = 0; k < 8; k++) acc[k] = acc[k] * sc + we * v[k];
            m = mn;
        } else {                              // fast path: we <= 2^8
            float we = exp2f(dot - m);
            l += we;
            #pragma unroll
            for (int k = 0; k < 8; k++) acc[k] = fmaf(we, v[k], acc[k]);
        }
    };

    int s = r0 + h;
    for (; s + 2 < r1; s += 4) {
        int c0 = colA[s], c1 = colA[s + 2];
        u16x8 v0 = *(const u16x8*)&xl[(size_t)c0 + lh * 8];
        u16x8 v1 = *(const u16x8*)&xl[(size_t)c1 + lh * 8];
        update(v0);
        update(v1);
    }
    for (; s < r1; s += 2) {
        int c = colA[s];
        u16x8 v = *(const u16x8*)&xl[(size_t)c + lh * 8];
        update(v);
    }

    // merge the two half-wave streams (lane i <-> lane i^32 hold same channels).
    // h=0 stream always non-empty (cnt>=1); empty h=1 stream contributes eo=0.
    float mq = (m == -INFINITY) ? -1e30f : m;   // avoid inf-inf in merge
    float mo = __shfl_xor(mq, 32);
    float lo = __shfl_xor(l, 32);
    float ms = fmaxf(mq, mo);
    float es = exp2f(mq - ms), eo = exp2f(mo - ms);
    float lt = l * es + lo * eo + 1e-16f;
    float inv = 1.f / lt;

    u16x8 o;
    #pragma unroll
    for (int k = 0; k < 8; k++) {
        float other = __shfl_xor(acc[k], 32);
        float r = (acc[k] * es + other * eo) * inv + bias[lh * 8 + k];
        o[k] = f2b(fmaxf(r, 0.f));
    }
    if (h == 0) *(u16x8*)&outp[(size_t)n * 256 + lh * 8] = o;
}

// ---------------- launch ----------------
extern "C" void kernel_launch(void* const* d_in, const int* in_sizes, int n_in,
                              void* d_out, int out_size, void* d_ws, size_t ws_size,
                              hipStream_t stream)
{
    const float* x    = (const float*)d_in[0];
    const int*   ei   = (const int*)d_in[1];
    const float* Wl1  = (const float*)d_in[2];
    const float* Wr1  = (const float*)d_in[3];
    const float* att1 = (const float*)d_in[4];
    const float* b1   = (const float*)d_in[5];
    const float* Wl2  = (const float*)d_in[6];
    const float* Wr2  = (const float*)d_in[7];
    const float* att2 = (const float*)d_in[8];
    const float* b2   = (const float*)d_in[9];
    const float* W3   = (const float*)d_in[10];
    const float* b3   = (const float*)d_in[11];
    const float* W4   = (const float*)d_in[12];
    const float* b4   = (const float*)d_in[13];

    const int N = in_sizes[0] / 128;       // 50000
    const int E = in_sizes[1] / 2;         // 650000
    const int* src  = ei;
    const int* dstv = ei + E;
    float* out = (float*)d_out;

    char* ws = (char*)d_ws;
    size_t o = 0;
    auto alloc = [&](size_t bytes) -> void* {
        void* p = ws + o;
        o += (bytes + 255) & ~(size_t)255;
        return p;
    };
    unsigned short* Wcat1  = (unsigned short*)alloc(512 * 128 * 2);  // [Wl1;Wr1]^T
    unsigned short* Wcat2  = (unsigned short*)alloc(512 * 256 * 2);  // [Wl2;Wr2]^T
    unsigned short* W34t   = (unsigned short*)alloc(256 * 256 * 2);  // (W3@W4)^T, 256 rows (pad 0)
    float*          b34    = (float*)alloc(128 * 4);
    unsigned short* xlb    = (unsigned short*)alloc((size_t)N * 256 * 2);
    unsigned short* xrb    = (unsigned short*)alloc((size_t)N * 256 * 2);
    unsigned short* h1b    = (unsigned short*)alloc((size_t)N * 256 * 2);
    unsigned short* h2b    = (unsigned short*)alloc((size_t)N * 256 * 2);
    int* cnt    = (int*)alloc((size_t)N * 4);
    int* colA   = (int*)alloc((size_t)N * CAP * 4);

    dim3 blk(256);

    // 1. cnt zero (DMA) + prep/fill combined
    hipMemsetAsync(cnt, 0, (size_t)N * 4, stream);
    k_prep<<<PEND, blk, 0, stream>>>(Wl1, Wr1, Wl2, Wr2, W3, W4, b3, b4,
                                     src, dstv, E, Wcat1, Wcat2, W34t, b34,
                                     cnt, colA);

    const int gy = (N + 127) / 128;        // 391

    // 2. Layer 1: [xl|xr] = x @ [Wl1|Wr1]  [N,128]@[128,512], wide tile, A read once
    gemm_mfma_w<<<dim3(1, gy), dim3(1024), 0, stream>>>(x, Wcat1, xlb, xrb,
                                                        N, 128, 256, 1);
    // 3.
    k_attn<<<(N + 3) / 4, blk, 0, stream>>>(xlb, xrb, att1, cnt, colA, b1, N, h1b);

    // 4. Layer 2: [N,256]@[256,512], wide tile, A read once
    gemm_mfma_w<<<dim3(1, gy), dim3(1024), 0, stream>>>(h1b, Wcat2, xlb, xrb,
                                                        N, 256, 256, 0);
    // 5.
    k_attn<<<(N + 3) / 4, blk, 0, stream>>>(xlb, xrb, att2, cnt, colA, b2, N, h2b);

    // 6. out = sigmoid(h2 @ W34 + b34)  [N,256]@[256,40]
    gemm_mfma<<<dim3(1, gy), dim3(512), 0, stream>>>(h2b, W34t, b34, out,
                                                     N, 256, 40);
}

// Round 13
// 252.777 us; speedup vs baseline: 1.0401x; 1.0401x over previous
//
#include <hip/hip_runtime.h>
#include <hip/hip_bf16.h>
#include <math.h>

typedef __attribute__((ext_vector_type(4))) float f32x4;
typedef __attribute__((ext_vector_type(8))) short s16x8;
typedef __attribute__((ext_vector_type(8))) unsigned short u16x8;

#define CAP 48   // bucket capacity per dst node; deg = 1 + Binomial(600k, 1/50k), P(>=48) ~ 1e-15

__device__ inline unsigned short f2b(float f) {
    union { float f; unsigned u; } x; x.f = f;
    unsigned r = x.u + 0x7FFF + ((x.u >> 16) & 1);   // RNE
    return (unsigned short)(r >> 16);
}
__device__ inline float b2f(unsigned short b) {
    union { unsigned u; float f; } x; x.u = ((unsigned)b) << 16; return x.f;
}

__device__ inline void gload_lds16(const void* g, void* l) {
    __builtin_amdgcn_global_load_lds(
        (const __attribute__((address_space(1))) void*)g,
        (__attribute__((address_space(3))) void*)l, 16, 0, 0);
}

// ---------------- bf16 MFMA GEMM, 128x256 tile, 8 waves ----------------
// A: aflt=0 -> bf16 [M,K] via global_load_lds; aflt=1 -> f32 [M,K], converted
// to bf16 during reg-staged LDS writes (fuses the x->bf16 cast into GEMM1).
// Bt [Nn,K] bf16 row-major (B pre-transposed).
// mode 0: bf16 split write: col<split -> C (stride split), else C2 (stride Nn-split)
// mode 2: f32 + bias + sigmoid -> C, only col<split stored, stride split
// R12 lesson: 128x512 wide tile regressed (worse occupancy/tail); keep 128x256.
#define GBM 128
#define GBN 256
#define GBK 64

__global__ __launch_bounds__(512) void gemm_mfma(
    const void* __restrict__ Aptr, const unsigned short* __restrict__ Bt,
    const float* __restrict__ bias, void* __restrict__ Cout, void* __restrict__ Cout2,
    int M, int Nn, int K, int split, int mode, int aflt)
{
    __shared__ unsigned short As[GBM * GBK];   // 16 KB
    __shared__ unsigned short Bs[GBN * GBK];   // 32 KB
    const int tid = threadIdx.x;
    const int lane = tid & 63;
    const int w = tid >> 6, wm = w >> 2, wn = w & 3;   // 2 x 4 waves of 64x64
    const int row0 = blockIdx.y * GBM, col0 = blockIdx.x * GBN;
    const int l15 = lane & 15, l7 = lane & 7, lhi = lane >> 4;

    f32x4 acc[4][4] = {};

    for (int k0 = 0; k0 < K; k0 += GBK) {
        if (aflt == 0) {
            const unsigned short* A = (const unsigned short*)Aptr;
            #pragma unroll
            for (int i = 0; i < 2; i++) {           // A: 1024 chunks of 16B
                int L = i * 512 + tid;
                int row = L >> 3;
                int c = (L & 7) ^ (row & 7);
                int gr = row0 + row; gr = gr < M ? gr : M - 1;
                gload_lds16(A + (size_t)gr * K + k0 + c * 8, (char*)As + L * 16);
            }
        } else {
            const float* A = (const float*)Aptr;
            #pragma unroll
            for (int i = 0; i < 2; i++) {           // A: f32 -> bf16 reg-staged
                int L = i * 512 + tid;
                int row = L >> 3;
                int c = (L & 7) ^ (row & 7);
                int gr = row0 + row; gr = gr < M ? gr : M - 1;
                const float* ap = A + (size_t)gr * K + k0 + c * 8;
                float4 va = *(const float4*)ap;
                float4 vb = *(const float4*)(ap + 4);
                ushort4 o0 = { f2b(va.x), f2b(va.y), f2b(va.z), f2b(va.w) };
                ushort4 o1 = { f2b(vb.x), f2b(vb.y), f2b(vb.z), f2b(vb.w) };
                *(ushort4*)((char*)As + L * 16)     = o0;
                *(ushort4*)((char*)As + L * 16 + 8) = o1;
            }
        }
        #pragma unroll
        for (int i = 0; i < 4; i++) {               // B: 2048 chunks
            int L = i * 512 + tid;
            int row = L >> 3;                       // 0..255
            int c = (L & 7) ^ (row & 7);
            gload_lds16(Bt + (size_t)(col0 + row) * K + k0 + c * 8, (char*)Bs + L * 16);
        }
        __syncthreads();                            // drains vmcnt + lgkmcnt
        #pragma unroll
        for (int kk = 0; kk < 2; kk++) {
            s16x8 af[4], bf[4];
            #pragma unroll
            for (int i = 0; i < 4; i++) {
                int slot = (wm * 64 + i * 16 + l15) * 8 + ((kk * 4 + lhi) ^ l7);
                af[i] = *(const s16x8*)((const char*)As + slot * 16);
            }
            #pragma unroll
            for (int j = 0; j < 4; j++) {
                int slot = (wn * 64 + j * 16 + l15) * 8 + ((kk * 4 + lhi) ^ l7);
                bf[j] = *(const s16x8*)((const char*)Bs + slot * 16);
            }
            #pragma unroll
            for (int i = 0; i < 4; i++)
                #pragma unroll
                for (int j = 0; j < 4; j++)
                    acc[i][j] = __builtin_amdgcn_mfma_f32_16x16x32_bf16(
                        af[i], bf[j], acc[i][j], 0, 0, 0);
        }
        __syncthreads();
    }

    // epilogue: C/D layout col=lane&15, row=(lane>>4)*4+reg (m89-verified)
    if (mode == 0) {
        unsigned short* C  = (unsigned short*)Cout;
        unsigned short* C2 = (unsigned short*)Cout2;
        const int ld2 = Nn - split;
        #pragma unroll
        for (int i = 0; i < 4; i++)
            #pragma unroll
            for (int r = 0; r < 4; r++) {
                int row = row0 + wm * 64 + i * 16 + lhi * 4 + r;
                if (row >= M) continue;
                #pragma unroll
                for (int j = 0; j < 4; j++) {
                    int col = col0 + wn * 64 + j * 16 + l15;
                    unsigned short val = f2b(acc[i][j][r]);
                    if (col < split) C[(size_t)row * split + col] = val;
                    else             C2[(size_t)row * ld2 + (col - split)] = val;
                }
            }
    } else {
        float* C = (float*)Cout;
        #pragma unroll
        for (int i = 0; i < 4; i++)
            #pragma unroll
            for (int r = 0; r < 4; r++) {
                int row = row0 + wm * 64 + i * 16 + lhi * 4 + r;
                if (row >= M) continue;
                #pragma unroll
                for (int j = 0; j < 4; j++) {
                    int col = col0 + wn * 64 + j * 16 + l15;
                    if (col >= split) continue;
                    float v = acc[i][j][r] + bias[col];
                    C[(size_t)row * split + col] = 1.f / (1.f + __expf(-v));
                }
            }
    }
}

// ---------------- prep + bucket-fill, one segmented launch ----------------
// [0,32):     Wcat1 = [Wl1^T; Wr1^T] bf16, 2048 elems/block
// [32,96):    Wcat2 = [Wl2^T; Wr2^T] bf16, 2048 elems/block
// [96,352):   W34t[n,:] = bf16((W3@W4)[:,n]) for n<40 else 0 (256 rows); b34
// [352,2892): bucket fill (cnt must be pre-zeroed via memset)
#define PB 32
#define PC 96
#define PD 352
#define PEND 2892

__global__ __launch_bounds__(256) void k_prep(
    const float* __restrict__ Wl1, const float* __restrict__ Wr1,
    const float* __restrict__ Wl2, const float* __restrict__ Wr2,
    const float* __restrict__ W3,  const float* __restrict__ W4,
    const float* __restrict__ b3,  const float* __restrict__ b4,
    const int* __restrict__ src,   const int* __restrict__ dstv, int E,
    unsigned short* __restrict__ Wcat1, unsigned short* __restrict__ Wcat2,
    unsigned short* __restrict__ W34t, float* __restrict__ b34,
    int* __restrict__ cnt, int* __restrict__ colA)
{
    __shared__ float w4c[128];
    const int b = blockIdx.x, tid = threadIdx.x;

    if (b < PB) {                                  // Wcat1 (65536)
        int base = b * 2048 + tid * 8;
        #pragma unroll
        for (int j = 0; j < 8; j++) {
            int e = base + j;
            int ep = e & 32767, n = ep >> 7, k = ep & 127;
            const float* srcp = (e < 32768) ? Wl1 : Wr1;
            Wcat1[e] = f2b(srcp[k * 256 + n]);
        }
    } else if (b < PC) {                           // Wcat2 (131072)
        int base = (b - PB) * 2048 + tid * 8;
        #pragma unroll
        for (int j = 0; j < 8; j++) {
            int e = base + j;
            int ep = e & 65535, n = ep >> 8, k = ep & 255;
            const float* srcp = (e < 65536) ? Wl2 : Wr2;
            Wcat2[e] = f2b(srcp[k * 256 + n]);
        }
    } else if (b < PD) {                           // W34 fold, n = b - PC (0..255)
        int n = b - PC;
        if (n < 40) {
            if (tid < 128) w4c[tid] = W4[tid * 40 + n];
            __syncthreads();
            float s = 0.f;
            const float4* p = (const float4*)&W3[(size_t)tid * 128];
            #pragma unroll
            for (int j = 0; j < 32; j++) {
                float4 v = p[j];
                s = fmaf(v.x, w4c[j * 4 + 0], s);
                s = fmaf(v.y, w4c[j * 4 + 1], s);
                s = fmaf(v.z, w4c[j * 4 + 2], s);
                s = fmaf(v.w, w4c[j * 4 + 3], s);
            }
            W34t[(size_t)n * 256 + tid] = f2b(s);
            if (tid == 0) {
                float t = b4[n];
                for (int j = 0; j < 128; j++) t = fmaf(b3[j], w4c[j], t);
                b34[n] = t;
            }
        } else {
            W34t[(size_t)n * 256 + tid] = 0;       // zero pad rows 40..255
        }
    } else {                                       // bucket fill (normal stores:
        int e = (b - PD) * 256 + tid;              //  colA is re-read by k_attn,
        if (e < E) {                               //  nt-store regressed in R12)
            int d = dstv[e];
            int slot = atomicAdd(&cnt[d], 1);
            colA[d * CAP + slot] = src[e] << 8;    // pre-multiplied row offset (x256)
        }
    }
}

// ---------------- fused attention (R11-exact: 2-deep, 40 VGPR floor config) ----------------
// One wave per dst node; two edge streams (one per 32-lane half), lane holds
// 8 channels (16B gathers), unroll x2 -> 4 gathers in flight per wave. Scores
// in exp2 domain (log2e folded into att). Defer-max (THR=8): fast path does
// single-FMA accumulate + one exp2; rescale only when ballot sees dot>m+8.
// Bracketed floor: VALU diet null (R6), extra VALU +7us (R7), 4-deep +3.4us (R10),
// nt-store colA +2us (R12). Do not touch.
__global__ __launch_bounds__(256) void k_attn(const unsigned short* __restrict__ xl,
    const unsigned short* __restrict__ xr, const float* __restrict__ att,
    const int* __restrict__ cnt, const int* __restrict__ colA,
    const float* __restrict__ bias, int Nn, unsigned short* __restrict__ outp)
{
    int n = blockIdx.x * 4 + (threadIdx.x >> 6);
    int lane = threadIdx.x & 63;
    if (n >= Nn) return;
    const int lh = lane & 31;        // lane-in-half: channels lh*8 .. lh*8+7
    const int h  = lane >> 5;        // edge-stream id
    int r0 = n * CAP;
    int r1 = r0 + cnt[n];            // cnt >= 1 always (self-loop)

    const float LOG2E = 1.4426950408889634f;
    u16x8 xb = *(const u16x8*)&xr[(size_t)n * 256 + lh * 8];
    float xrv[8], w[8];
    #pragma unroll
    for (int k = 0; k < 8; k++) { xrv[k] = b2f(xb[k]); w[k] = att[lh * 8 + k] * LOG2E; }

    float m = -INFINITY, l = 0.f;
    float acc[8] = {};

    auto update = [&](const u16x8& vb) {
        float v[8];
        #pragma unroll
        for (int k = 0; k < 8; k++) v[k] = b2f(vb[k]);
        float dot = 0.f;
        #pragma unroll
        for (int k = 0; k < 8; k++) {
            float t = v[k] + xrv[k];
            t = fmaxf(t, 0.2f * t);          // leaky_relu, slope<1
            dot = fmaf(t, w[k], dot);
        }
        #pragma unroll
        for (int off = 1; off <= 8; off <<= 1) dot += __shfl_xor(dot, off);
        // dot uniform within each 16-lane head group, exp2 domain
        if (__ballot(dot > m + 8.f)) {       // rare rescale path
            float mn = fmaxf(m, dot);
            float sc = exp2f(m - mn);        // 0 on first edge (m=-inf)
            float we = exp2f(dot - mn);
            l = l * sc + we;
            #pragma unroll
            for (int k = 0; k < 8; k++) acc[k] = acc[k] * sc + we * v[k];
            m = mn;
        } else {                              // fast path: we <= 2^8
            float we = exp2f(dot - m);
            l += we;
            #pragma unroll
            for (int k = 0; k < 8; k++) acc[k] = fmaf(we, v[k], acc[k]);
        }
    };

    int s = r0 + h;
    for (; s + 2 < r1; s += 4) {
        int c0 = colA[s], c1 = colA[s + 2];
        u16x8 v0 = *(const u16x8*)&xl[(size_t)c0 + lh * 8];
        u16x8 v1 = *(const u16x8*)&xl[(size_t)c1 + lh * 8];
        update(v0);
        update(v1);
    }
    for (; s < r1; s += 2) {
        int c = colA[s];
        u16x8 v = *(const u16x8*)&xl[(size_t)c + lh * 8];
        update(v);
    }

    // merge the two half-wave streams (lane i <-> lane i^32 hold same channels).
    // h=0 stream always non-empty (cnt>=1); empty h=1 stream contributes eo=0.
    float mq = (m == -INFINITY) ? -1e30f : m;   // avoid inf-inf in merge
    float mo = __shfl_xor(mq, 32);
    float lo = __shfl_xor(l, 32);
    float ms = fmaxf(mq, mo);
    float es = exp2f(mq - ms), eo = exp2f(mo - ms);
    float lt = l * es + lo * eo + 1e-16f;
    float inv = 1.f / lt;

    u16x8 o;
    #pragma unroll
    for (int k = 0; k < 8; k++) {
        float other = __shfl_xor(acc[k], 32);
        float r = (acc[k] * es + other * eo) * inv + bias[lh * 8 + k];
        o[k] = f2b(fmaxf(r, 0.f));
    }
    if (h == 0) *(u16x8*)&outp[(size_t)n * 256 + lh * 8] = o;
}

// ---------------- launch ----------------
extern "C" void kernel_launch(void* const* d_in, const int* in_sizes, int n_in,
                              void* d_out, int out_size, void* d_ws, size_t ws_size,
                              hipStream_t stream)
{
    const float* x    = (const float*)d_in[0];
    const int*   ei   = (const int*)d_in[1];
    const float* Wl1  = (const float*)d_in[2];
    const float* Wr1  = (const float*)d_in[3];
    const float* att1 = (const float*)d_in[4];
    const float* b1   = (const float*)d_in[5];
    const float* Wl2  = (const float*)d_in[6];
    const float* Wr2  = (const float*)d_in[7];
    const float* att2 = (const float*)d_in[8];
    const float* b2   = (const float*)d_in[9];
    const float* W3   = (const float*)d_in[10];
    const float* b3   = (const float*)d_in[11];
    const float* W4   = (const float*)d_in[12];
    const float* b4   = (const float*)d_in[13];

    const int N = in_sizes[0] / 128;       // 50000
    const int E = in_sizes[1] / 2;         // 650000
    const int* src  = ei;
    const int* dstv = ei + E;
    float* out = (float*)d_out;

    char* ws = (char*)d_ws;
    size_t o = 0;
    auto alloc = [&](size_t bytes) -> void* {
        void* p = ws + o;
        o += (bytes + 255) & ~(size_t)255;
        return p;
    };
    unsigned short* Wcat1  = (unsigned short*)alloc(512 * 128 * 2);  // [Wl1;Wr1]^T
    unsigned short* Wcat2  = (unsigned short*)alloc(512 * 256 * 2);  // [Wl2;Wr2]^T
    unsigned short* W34t   = (unsigned short*)alloc(256 * 256 * 2);  // (W3@W4)^T, 256 rows (pad 0)
    float*          b34    = (float*)alloc(128 * 4);
    unsigned short* xlb    = (unsigned short*)alloc((size_t)N * 256 * 2);
    unsigned short* xrb    = (unsigned short*)alloc((size_t)N * 256 * 2);
    unsigned short* h1b    = (unsigned short*)alloc((size_t)N * 256 * 2);
    unsigned short* h2b    = (unsigned short*)alloc((size_t)N * 256 * 2);
    int* cnt    = (int*)alloc((size_t)N * 4);
    int* colA   = (int*)alloc((size_t)N * CAP * 4);

    dim3 blk(256);

    // 1. cnt zero (DMA) + prep/fill combined
    hipMemsetAsync(cnt, 0, (size_t)N * 4, stream);
    k_prep<<<PEND, blk, 0, stream>>>(Wl1, Wr1, Wl2, Wr2, W3, W4, b3, b4,
                                     src, dstv, E, Wcat1, Wcat2, W34t, b34,
                                     cnt, colA);

    const int gy = (N + GBM - 1) / GBM;    // 391

    // 2. Layer 1: [xl|xr] = x @ [Wl1|Wr1]   [N,128]@[128,512], f32-A fused cvt
    gemm_mfma<<<dim3(2, gy), dim3(512), 0, stream>>>(x, Wcat1, nullptr, xlb, xrb,
                                                     N, 512, 128, 256, 0, 1);
    // 3.
    k_attn<<<(N + 3) / 4, blk, 0, stream>>>(xlb, xrb, att1, cnt, colA, b1, N, h1b);

    // 4. Layer 2: [N,256]@[256,512], split-write
    gemm_mfma<<<dim3(2, gy), dim3(512), 0, stream>>>(h1b, Wcat2, nullptr, xlb, xrb,
                                                     N, 512, 256, 256, 0, 0);
    // 5.
    k_attn<<<(N + 3) / 4, blk, 0, stream>>>(xlb, xrb, att2, cnt, colA, b2, N, h2b);

    // 6. out = sigmoid(h2 @ W34 + b34)  [N,256]@[256,40]
    gemm_mfma<<<dim3(1, gy), dim3(512), 0, stream>>>(h2b, W34t, b34, out, nullptr,
                                                     N, 128, 256, 40, 2, 0);
}